// Round 4
// baseline (228.878 us; speedup 1.0000x reference)
//
#include <hip/hip_runtime.h>

// RandomShiftsAug: the reference's grid_sample reduces exactly to an
// integer-pixel shift with replicate clamping:
//   out[n,c,oy,ox] = x[n,c, clamp(oy+sy-pad,0,H-1), clamp(ox+sx-pad,0,W-1)]
// (ix == ox + sx exactly; bilinear weights degenerate to {1,0}).
//
// R4: amortize index math + edge-fixup over 3 channels per thread
// (sx,sy depend only on n; k0..k3 only on ox4,sx). 3 independent 16B
// loads in flight per lane (MLP), 3 nontemporal 16B stores.

#define NN 512
#define CC 9
#define HH 84
#define WW 84

typedef float f4u __attribute__((ext_vector_type(4), aligned(4)));   // load, 4B-aligned
typedef float f4a __attribute__((ext_vector_type(4)));               // store, 16B-aligned

__device__ __forceinline__ float sel4(f4u w, int k) {
    return k == 0 ? w.x : (k == 1 ? w.y : (k == 2 ? w.z : w.w));
}

__global__ __launch_bounds__(256) void random_shift_kernel(
    const float* __restrict__ x,
    const int* __restrict__ shift,
    const int* __restrict__ pad_p,
    float* __restrict__ out)
{
    const int pad = pad_p[0];
    const int W4 = WW / 4;                         // 21
    const int total = NN * 3 * HH * W4;            // 2,709,504
    int idx = blockIdx.x * blockDim.x + threadIdx.x;
    if (idx >= total) return;

    int ox4 = idx % W4;
    int t   = idx / W4;
    int oy  = t % HH;
    t      /= HH;
    int cg  = t % 3;                               // channel group: {3cg, 3cg+1, 3cg+2}
    int n   = t / 3;

    // shift[n,0,0,0] = x-shift (width), shift[n,0,0,1] = y-shift (height)
    int sx = shift[2 * n + 0] - pad;
    int sy = shift[2 * n + 1] - pad;

    int sry = min(max(oy + sy, 0), HH - 1);

    int ox = ox4 * 4;
    int s  = ox + sx;                 // window start in source row
    int a  = min(max(s, 0), WW - 4);  // clamped window start (interior: a==s)

    // element j wants src[clamp(s+j,0,W-1)] which lies in [a, a+3]
    int k0 = min(max(s + 0, 0), WW - 1) - a;
    int k1 = min(max(s + 1, 0), WW - 1) - a;
    int k2 = min(max(s + 2, 0), WW - 1) - a;
    int k3 = min(max(s + 3, 0), WW - 1) - a;

    int c0 = 3 * cg;
    const size_t plane = (size_t)HH * WW;          // 7056
    const float* __restrict__ src0 =
        x + ((size_t)(n * CC + c0) * HH + sry) * WW + a;
    float* __restrict__ dst0 =
        out + ((size_t)(n * CC + c0) * HH + oy) * WW + ox;

    f4u w0 = *(const f4u*)(src0);
    f4u w1 = *(const f4u*)(src0 + plane);
    f4u w2 = *(const f4u*)(src0 + 2 * plane);

    f4a v0, v1, v2;
    v0.x = sel4(w0, k0); v0.y = sel4(w0, k1); v0.z = sel4(w0, k2); v0.w = sel4(w0, k3);
    v1.x = sel4(w1, k0); v1.y = sel4(w1, k1); v1.z = sel4(w1, k2); v1.w = sel4(w1, k3);
    v2.x = sel4(w2, k0); v2.y = sel4(w2, k1); v2.z = sel4(w2, k2); v2.w = sel4(w2, k3);

    __builtin_nontemporal_store(v0, (f4a*)(dst0));
    __builtin_nontemporal_store(v1, (f4a*)(dst0 + plane));
    __builtin_nontemporal_store(v2, (f4a*)(dst0 + 2 * plane));
}

extern "C" void kernel_launch(void* const* d_in, const int* in_sizes, int n_in,
                              void* d_out, int out_size, void* d_ws, size_t ws_size,
                              hipStream_t stream)
{
    const float* x     = (const float*)d_in[0];
    const int*   shift = (const int*)d_in[1];
    const int*   pad   = (const int*)d_in[2];
    float*       out   = (float*)d_out;

    const int total  = NN * 3 * HH * (WW / 4);
    const int block  = 256;
    const int grid   = (total + block - 1) / block;
    random_shift_kernel<<<grid, block, 0, stream>>>(x, shift, pad, out);
}

// Round 5
// 221.678 us; speedup vs baseline: 1.0325x; 1.0325x over previous
//
#include <hip/hip_runtime.h>

// RandomShiftsAug: the reference's grid_sample reduces exactly to an
// integer-pixel shift with replicate clamping:
//   out[n,c,oy,ox] = x[n,c, clamp(oy+sy-pad,0,H-1), clamp(ox+sx-pad,0,W-1)]
// (ix == ox + sx exactly; bilinear weights degenerate to {1,0}).
//
// R5: back to R3's 1-float4-per-thread structure (R4's 3-channel variant
// regressed: 77.4us vs ~70us, VALUBusy only 10.8% so index-math
// amortization bought nothing). Single experiment variable vs R3:
// PLAIN store instead of nontemporal — let the 130MB output stream land
// in L2/L3 (256MB Infinity Cache) and write back lazily instead of
// forcing all 128MB to HBM inside the kernel (R4 counter: WRITE_SIZE
// was the full 128MB with nt).

#define NN 512
#define CC 9
#define HH 84
#define WW 84

typedef float f4u __attribute__((ext_vector_type(4), aligned(4)));   // load, 4B-aligned
typedef float f4a __attribute__((ext_vector_type(4)));               // store, 16B-aligned

__device__ __forceinline__ float sel4(f4u w, int k) {
    return k == 0 ? w.x : (k == 1 ? w.y : (k == 2 ? w.z : w.w));
}

__global__ __launch_bounds__(256) void random_shift_kernel(
    const float* __restrict__ x,
    const int* __restrict__ shift,
    const int* __restrict__ pad_p,
    float* __restrict__ out)
{
    const int pad = pad_p[0];
    const int W4 = WW / 4;                       // 21
    const int total = NN * CC * HH * W4;         // 8,128,512
    int idx = blockIdx.x * blockDim.x + threadIdx.x;
    if (idx >= total) return;

    int ox4 = idx % W4;
    int t   = idx / W4;
    int oy  = t % HH;
    int np  = t / HH;                            // n*CC + c (plane index)
    int n   = np / CC;

    // shift[n,0,0,0] = x-shift (width), shift[n,0,0,1] = y-shift (height)
    int sx = shift[2 * n + 0] - pad;
    int sy = shift[2 * n + 1] - pad;

    int sry = min(max(oy + sy, 0), HH - 1);
    const float* __restrict__ src =
        x + ((size_t)np * HH + sry) * WW;

    int ox = ox4 * 4;
    int s  = ox + sx;                 // window start in source row
    int a  = min(max(s, 0), WW - 4);  // clamped window start (interior: a==s)

    f4u w = *(const f4u*)(src + a);   // one 16B load, 4B-aligned

    // element j wants src[clamp(s+j,0,W-1)] which lies in [a, a+3]
    int k0 = min(max(s + 0, 0), WW - 1) - a;
    int k1 = min(max(s + 1, 0), WW - 1) - a;
    int k2 = min(max(s + 2, 0), WW - 1) - a;
    int k3 = min(max(s + 3, 0), WW - 1) - a;

    f4a v;
    v.x = sel4(w, k0);
    v.y = sel4(w, k1);
    v.z = sel4(w, k2);
    v.w = sel4(w, k3);

    f4a* __restrict__ dst =
        (f4a*)(out + ((size_t)np * HH + oy) * WW + ox);
    *dst = v;                          // plain store: L2/L3-absorbed
}

extern "C" void kernel_launch(void* const* d_in, const int* in_sizes, int n_in,
                              void* d_out, int out_size, void* d_ws, size_t ws_size,
                              hipStream_t stream)
{
    const float* x     = (const float*)d_in[0];
    const int*   shift = (const int*)d_in[1];
    const int*   pad   = (const int*)d_in[2];
    float*       out   = (float*)d_out;

    const int total  = NN * CC * HH * (WW / 4);
    const int block  = 256;
    const int grid   = (total + block - 1) / block;
    random_shift_kernel<<<grid, block, 0, stream>>>(x, shift, pad, out);
}